// Round 7
// baseline (196.776 us; speedup 1.0000x reference)
//
#include <hip/hip_runtime.h>

#define IMG_H 512
#define IMG_W 512
#define NPLANES 48
#define TX 64          // tile width
#define TY 16          // rows per half-tile; each block processes two halves
#define VSTRIDE 76     // %4==0: H-pass bases 16B-aligned -> b128 reads
#define NF 5
#define BLOCK 256

// Gaussian window (WINDOW=11, sigma=1.5), normalized; computed offline in
// double precision. rel err ~1e-8 vs reference's float64->float32 window.
static constexpr float WG[11] = {
    0.0010283804f, 0.0075987582f, 0.0360007723f, 0.1093606901f,
    0.2130055377f, 0.2660117259f, 0.2130055377f, 0.1093606901f,
    0.0360007723f, 0.0075987582f, 0.0010283804f
};

// Phase A: main vertical pass. Exactly 256 tasks: wave rq (0..3) handles
// row-quad rq, lane handles staged col 5+lane (gx = x0+lane, never x-OOB).
// Interior path uses a 32-bit voffset walk (saddr+voffset loads, no 64-bit
// per-load address adds).
template <bool YB>
__device__ __forceinline__ void vpassA(const float* __restrict__ i1,
                                       const float* __restrict__ i2,
                                       float* __restrict__ vs,
                                       int x0, int y0, int tid) {
    const int rq   = tid >> 6;          // 0..3
    const int lane = tid & 63;
    const int c    = 5 + lane;          // staged col 5..68
    const int gx   = x0 + lane;         // always in [0,512)
    const int gy0  = y0 + (rq << 2) - 5;

    float acc[NF][4];
    #pragma unroll
    for (int f = 0; f < NF; ++f)
        #pragma unroll
        for (int j = 0; j < 4; ++j) acc[f][j] = 0.f;

    const int voff0 = gy0 * IMG_W + gx;   // 32-bit, fits (<2^18)
    #pragma unroll
    for (int i = 0; i < 14; ++i) {
        float a, b;
        if (YB) {
            int gy = gy0 + i;
            bool ok = (unsigned)gy < IMG_H;
            int g = ok ? gy * IMG_W + gx : 0;
            a = i1[g]; b = i2[g];
            a = ok ? a : 0.f;
            b = ok ? b : 0.f;
        } else {
            int v = voff0 + i * IMG_W;
            a = i1[v];
            b = i2[v];
        }
        float aa = a * a, bb = b * b, ab = a * b;
        #pragma unroll
        for (int j = 0; j < 4; ++j) {
            int k = i - j;                    // compile-time per (i,j)
            if (k >= 0 && k < 11) {
                acc[0][j] += WG[k] * a;
                acc[1][j] += WG[k] * b;
                acc[2][j] += WG[k] * aa;
                acc[3][j] += WG[k] * bb;
                acc[4][j] += WG[k] * ab;
            }
        }
    }
    #pragma unroll
    for (int f = 0; f < NF; ++f)
        #pragma unroll
        for (int j = 0; j < 4; ++j)
            vs[f * TY * VSTRIDE + ((rq << 2) + j) * VSTRIDE + c] = acc[f][j];
}

// Phase B: halo columns (staged cols 0..4 and 69..73), single-row tasks.
// 160 tasks on threads 0..159; fully guarded (cheap, rare).
__device__ __forceinline__ void vpassB(const float* __restrict__ i1,
                                       const float* __restrict__ i2,
                                       float* __restrict__ vs,
                                       int x0, int y0, int t) {
    int row = t / 10;                 // 0..15
    int m   = t - row * 10;           // 0..9
    int c   = (m < 5) ? m : m + 64;   // staged col
    int gx  = x0 - 5 + c;
    int gy0 = y0 + row - 5;
    float s0 = 0.f, s1 = 0.f, s2 = 0.f, s3 = 0.f, s4 = 0.f;
    #pragma unroll
    for (int k = 0; k < 11; ++k) {
        int gy = gy0 + k;
        bool ok = ((unsigned)gy < IMG_H) & ((unsigned)gx < IMG_W);
        int g = ok ? gy * IMG_W + gx : 0;
        float a = i1[g], b = i2[g];
        a = ok ? a : 0.f;
        b = ok ? b : 0.f;
        s0 += WG[k] * a;
        s1 += WG[k] * b;
        s2 += WG[k] * (a * a);
        s3 += WG[k] * (b * b);
        s4 += WG[k] * (a * b);
    }
    int o = row * VSTRIDE + c;
    vs[0 * TY * VSTRIDE + o] = s0;
    vs[1 * TY * VSTRIDE + o] = s1;
    vs[2 * TY * VSTRIDE + o] = s2;
    vs[3 * TY * VSTRIDE + o] = s3;
    vs[4 * TY * VSTRIDE + o] = s4;
}

// Horizontal pass + SSIM: exactly one (row, col-quad) task per thread.
__device__ __forceinline__ float hpass_ssim(const float* __restrict__ vs, int tid) {
    int r  = tid >> 4;                // 0..15
    int c0 = (tid & 15) << 2;         // 0..60
    float acc[NF][4];
    #pragma unroll
    for (int f = 0; f < NF; ++f) {
        const float* vp = vs + (f * TY + r) * VSTRIDE + c0;
        float4 q0 = *reinterpret_cast<const float4*>(vp);
        float4 q1 = *reinterpret_cast<const float4*>(vp + 4);
        float4 q2 = *reinterpret_cast<const float4*>(vp + 8);
        float2 q3 = *reinterpret_cast<const float2*>(vp + 12);
        float hv[14] = {q0.x, q0.y, q0.z, q0.w, q1.x, q1.y, q1.z, q1.w,
                        q2.x, q2.y, q2.z, q2.w, q3.x, q3.y};
        #pragma unroll
        for (int j = 0; j < 4; ++j) {
            float s = 0.f;
            #pragma unroll
            for (int k = 0; k < 11; ++k) s += WG[k] * hv[k + j];
            acc[f][j] = s;
        }
    }
    float lsum = 0.f;
    #pragma unroll
    for (int j = 0; j < 4; ++j) {
        float mu1 = acc[0][j], mu2 = acc[1][j];
        float ex2 = acc[2][j], ey2 = acc[3][j], exy = acc[4][j];
        float mu1s = mu1 * mu1;
        float mu2s = mu2 * mu2;
        float mu12 = mu1 * mu2;
        float s1q = ex2 - mu1s;
        float s2q = ey2 - mu2s;
        float s12 = exy - mu12;
        float v1 = 2.f * s12 + 9e-4f;
        float v2 = s1q + s2q + 9.01e-4f;          // C2 + 1e-6
        float num = (2.f * mu12 + 1e-4f) * v1;    // C1 = 1e-4
        float den = (mu1s + mu2s + 1e-4f) * v2;
        lsum += num * __builtin_amdgcn_rcpf(den); // 1-ulp rcp
    }
    return lsum;
}

// Empirical hipcc law: VGPR cap = 256/k. k=4 -> cap 64 -> 8-waves/SIMD class.
// Natural need was 72 at cap 128; gap of 8 should close by scheduling, not
// spill (r4/r5 spilled with gaps of 33-42). Tripwire: WRITE_SIZE >> 0.2 MB.
// Occupancy ceiling: LDS 24.3KB -> 6 blocks/CU = 24 waves/CU (75% class).
__global__ __launch_bounds__(BLOCK, 4)
void ssim_main(const float* __restrict__ img1, const float* __restrict__ img2,
               float* __restrict__ blocksums) {
    __shared__ float vs[NF * TY * VSTRIDE];   // 24320 B
    __shared__ float red[4];

    const int tid = threadIdx.x;
    const int x0 = blockIdx.x * TX;
    const float* i1 = img1 + (size_t)blockIdx.z * (IMG_H * IMG_W);
    const float* i2 = img2 + (size_t)blockIdx.z * (IMG_H * IMG_W);

    float lsum = 0.f;
    for (int half = 0; half < 2; ++half) {
        int y0 = blockIdx.y * 32 + half * TY;
        bool yb = (half == 0) ? (blockIdx.y == 0)
                              : (blockIdx.y == gridDim.y - 1);
        if (yb) vpassA<true >(i1, i2, vs, x0, y0, tid);
        else    vpassA<false>(i1, i2, vs, x0, y0, tid);
        if (tid < 160) vpassB(i1, i2, vs, x0, y0, tid);
        __syncthreads();
        lsum += hpass_ssim(vs, tid);
        __syncthreads();   // vs reused by next half
    }

    // block reduction -> one float per block (every slot written every launch)
    #pragma unroll
    for (int off = 32; off; off >>= 1) lsum += __shfl_down(lsum, off, 64);
    if ((tid & 63) == 0) red[tid >> 6] = lsum;
    __syncthreads();
    if (tid == 0) {
        float bs = red[0] + red[1] + red[2] + red[3];
        int bid = (blockIdx.z * gridDim.y + blockIdx.y) * gridDim.x + blockIdx.x;
        blocksums[bid] = bs;
    }
}

__global__ void ssim_finalize(const float* __restrict__ bs, float* __restrict__ out, int n) {
    __shared__ double red[4];
    double s = 0.0;
    for (int i = threadIdx.x; i < n; i += BLOCK) s += (double)bs[i];
    #pragma unroll
    for (int off = 32; off; off >>= 1) s += __shfl_down(s, off, 64);
    if ((threadIdx.x & 63) == 0) red[threadIdx.x >> 6] = s;
    __syncthreads();
    if (threadIdx.x == 0)
        out[0] = (float)((red[0] + red[1] + red[2] + red[3]) / 12582912.0);
}

extern "C" void kernel_launch(void* const* d_in, const int* in_sizes, int n_in,
                              void* d_out, int out_size, void* d_ws, size_t ws_size,
                              hipStream_t stream) {
    const float* img1 = (const float*)d_in[0];
    const float* img2 = (const float*)d_in[1];
    float* out = (float*)d_out;
    float* bsums = (float*)d_ws;   // 6144 floats, all written every launch

    dim3 grid(IMG_W / TX, IMG_H / 32, NPLANES);   // 8 x 16 x 48 = 6144 blocks
    ssim_main<<<grid, BLOCK, 0, stream>>>(img1, img2, bsums);
    ssim_finalize<<<1, BLOCK, 0, stream>>>(bsums, out, 6144);
}

// Round 10
// 178.650 us; speedup vs baseline: 1.1015x; 1.1015x over previous
//
#include <hip/hip_runtime.h>

#define IMG_H 512
#define IMG_W 512
#define NPLANES 48
#define TX 64          // tile width
#define TY 16          // rows per half-tile; each block processes two halves
#define VSTRIDE 76     // %4==0: H-pass bases 16B-aligned -> b128 reads
#define NF 4           // fields: x, y, (x+y)^2, (x-y)^2   (4xy = P - M)
#define BLOCK 256

// Gaussian window (WINDOW=11, sigma=1.5), normalized; computed offline in
// double precision. rel err ~1e-8 vs reference's float64->float32 window.
static constexpr float WG[11] = {
    0.0010283804f, 0.0075987582f, 0.0360007723f, 0.1093606901f,
    0.2130055377f, 0.2660117259f, 0.2130055377f, 0.1093606901f,
    0.0360007723f, 0.0075987582f, 0.0010283804f
};

// Phase A: main vertical pass. Exactly 256 tasks: wave rq (0..3) handles
// row-quad rq, lane handles staged col 5+lane (gx = x0+lane, never x-OOB).
template <bool YB>
__device__ __forceinline__ void vpassA(const float* __restrict__ i1,
                                       const float* __restrict__ i2,
                                       float* __restrict__ vs,
                                       int x0, int y0, int tid) {
    const int rq   = tid >> 6;          // 0..3
    const int lane = tid & 63;
    const int c    = 5 + lane;          // staged col 5..68
    const int gx   = x0 + lane;         // always in [0,512)
    const int gy0  = y0 + (rq << 2) - 5;

    float acc[NF][4];
    #pragma unroll
    for (int f = 0; f < NF; ++f)
        #pragma unroll
        for (int j = 0; j < 4; ++j) acc[f][j] = 0.f;

    const int voff0 = gy0 * IMG_W + gx;   // 32-bit offset walk
    #pragma unroll
    for (int i = 0; i < 14; ++i) {
        float a, b;
        if (YB) {
            int gy = gy0 + i;
            bool ok = (unsigned)gy < IMG_H;
            int g = ok ? gy * IMG_W + gx : 0;
            a = i1[g]; b = i2[g];
            a = ok ? a : 0.f;
            b = ok ? b : 0.f;
        } else {
            int v = voff0 + i * IMG_W;
            a = i1[v];
            b = i2[v];
        }
        float s = a + b, d = a - b;
        float ss = s * s, dd = d * d;
        #pragma unroll
        for (int j = 0; j < 4; ++j) {
            int k = i - j;                    // compile-time per (i,j)
            if (k >= 0 && k < 11) {
                acc[0][j] += WG[k] * a;
                acc[1][j] += WG[k] * b;
                acc[2][j] += WG[k] * ss;
                acc[3][j] += WG[k] * dd;
            }
        }
    }
    #pragma unroll
    for (int f = 0; f < NF; ++f)
        #pragma unroll
        for (int j = 0; j < 4; ++j)
            vs[f * TY * VSTRIDE + ((rq << 2) + j) * VSTRIDE + c] = acc[f][j];
}

// Phase B: halo columns (staged cols 0..4 and 69..73), single-row tasks.
// 160 tasks on threads 0..159; fully guarded (cheap, rare).
__device__ __forceinline__ void vpassB(const float* __restrict__ i1,
                                       const float* __restrict__ i2,
                                       float* __restrict__ vs,
                                       int x0, int y0, int t) {
    int row = t / 10;                 // 0..15
    int m   = t - row * 10;           // 0..9
    int c   = (m < 5) ? m : m + 64;   // staged col
    int gx  = x0 - 5 + c;
    int gy0 = y0 + row - 5;
    float s0 = 0.f, s1 = 0.f, s2 = 0.f, s3 = 0.f;
    #pragma unroll
    for (int k = 0; k < 11; ++k) {
        int gy = gy0 + k;
        bool ok = ((unsigned)gy < IMG_H) & ((unsigned)gx < IMG_W);
        int g = ok ? gy * IMG_W + gx : 0;
        float a = i1[g], b = i2[g];
        a = ok ? a : 0.f;
        b = ok ? b : 0.f;
        float s = a + b, d = a - b;
        s0 += WG[k] * a;
        s1 += WG[k] * b;
        s2 += WG[k] * (s * s);
        s3 += WG[k] * (d * d);
    }
    int o = row * VSTRIDE + c;
    vs[0 * TY * VSTRIDE + o] = s0;
    vs[1 * TY * VSTRIDE + o] = s1;
    vs[2 * TY * VSTRIDE + o] = s2;
    vs[3 * TY * VSTRIDE + o] = s3;
}

// Horizontal pass + SSIM: exactly one (row, col-quad) task per thread.
__device__ __forceinline__ float hpass_ssim(const float* __restrict__ vs, int tid) {
    int r  = tid >> 4;                // 0..15
    int c0 = (tid & 15) << 2;         // 0..60
    float acc[NF][4];
    #pragma unroll
    for (int f = 0; f < NF; ++f) {
        const float* vp = vs + (f * TY + r) * VSTRIDE + c0;
        float4 q0 = *reinterpret_cast<const float4*>(vp);
        float4 q1 = *reinterpret_cast<const float4*>(vp + 4);
        float4 q2 = *reinterpret_cast<const float4*>(vp + 8);
        float2 q3 = *reinterpret_cast<const float2*>(vp + 12);
        float hv[14] = {q0.x, q0.y, q0.z, q0.w, q1.x, q1.y, q1.z, q1.w,
                        q2.x, q2.y, q2.z, q2.w, q3.x, q3.y};
        #pragma unroll
        for (int j = 0; j < 4; ++j) {
            float s = 0.f;
            #pragma unroll
            for (int k = 0; k < 11; ++k) s += WG[k] * hv[k + j];
            acc[f][j] = s;
        }
    }
    float lsum = 0.f;
    #pragma unroll
    for (int j = 0; j < 4; ++j) {
        float mu1 = acc[0][j], mu2 = acc[1][j];
        float Pv  = acc[2][j], Mv  = acc[3][j];
        float mu1s = mu1 * mu1;
        float mu2s = mu2 * mu2;
        float mu12 = mu1 * mu2;
        // 2*sigma12 + C2 = (P-M)/2 - 2*mu12 + C2
        float v1 = 0.5f * (Pv - Mv) - 2.f * mu12 + 9e-4f;
        // sigma1^2+sigma2^2 + C2 + eps = (P+M)/2 - mu1^2 - mu2^2 + C2 + eps
        float v2 = 0.5f * (Pv + Mv) - mu1s - mu2s + 9.01e-4f;
        float num = (2.f * mu12 + 1e-4f) * v1;    // C1 = 1e-4
        float den = (mu1s + mu2s + 1e-4f) * v2;
        lsum += num * __builtin_amdgcn_rcpf(den); // 1-ulp rcp
    }
    return lsum;
}

// VGPR cap = 256/k -> k=4 caps at 64. 4-field cut accumulators 20->16, so the
// natural need (~72 at 5 fields) should now FIT 64 without spill.
// Tripwire: WRITE_SIZE >> 0.2 MB means spill -> revert to k=2 next round.
// Ceilings: LDS 19.5KB -> 8 blocks/CU; VGPR<=64 -> 32 waves/CU (100% class).
__global__ __launch_bounds__(BLOCK, 4)
void ssim_main(const float* __restrict__ img1, const float* __restrict__ img2,
               float* __restrict__ blocksums) {
    __shared__ float vs[NF * TY * VSTRIDE];   // 19456 B
    __shared__ float red[4];

    const int tid = threadIdx.x;
    const int x0 = blockIdx.x * TX;
    const float* i1 = img1 + (size_t)blockIdx.z * (IMG_H * IMG_W);
    const float* i2 = img2 + (size_t)blockIdx.z * (IMG_H * IMG_W);

    float lsum = 0.f;
    for (int half = 0; half < 2; ++half) {
        int y0 = blockIdx.y * 32 + half * TY;
        bool yb = (half == 0) ? (blockIdx.y == 0)
                              : (blockIdx.y == gridDim.y - 1);
        if (yb) vpassA<true >(i1, i2, vs, x0, y0, tid);
        else    vpassA<false>(i1, i2, vs, x0, y0, tid);
        if (tid < 160) vpassB(i1, i2, vs, x0, y0, tid);
        __syncthreads();
        lsum += hpass_ssim(vs, tid);
        __syncthreads();   // vs reused by next half
    }

    // block reduction -> one float per block (every slot written every launch)
    #pragma unroll
    for (int off = 32; off; off >>= 1) lsum += __shfl_down(lsum, off, 64);
    if ((tid & 63) == 0) red[tid >> 6] = lsum;
    __syncthreads();
    if (tid == 0) {
        float bs = red[0] + red[1] + red[2] + red[3];
        int bid = (blockIdx.z * gridDim.y + blockIdx.y) * gridDim.x + blockIdx.x;
        blocksums[bid] = bs;
    }
}

__global__ void ssim_finalize(const float* __restrict__ bs, float* __restrict__ out, int n) {
    __shared__ double red[4];
    double s = 0.0;
    for (int i = threadIdx.x; i < n; i += BLOCK) s += (double)bs[i];
    #pragma unroll
    for (int off = 32; off; off >>= 1) s += __shfl_down(s, off, 64);
    if ((threadIdx.x & 63) == 0) red[threadIdx.x >> 6] = s;
    __syncthreads();
    if (threadIdx.x == 0)
        out[0] = (float)((red[0] + red[1] + red[2] + red[3]) / 12582912.0);
}

extern "C" void kernel_launch(void* const* d_in, const int* in_sizes, int n_in,
                              void* d_out, int out_size, void* d_ws, size_t ws_size,
                              hipStream_t stream) {
    const float* img1 = (const float*)d_in[0];
    const float* img2 = (const float*)d_in[1];
    float* out = (float*)d_out;
    float* bsums = (float*)d_ws;   // 6144 floats, all written every launch

    dim3 grid(IMG_W / TX, IMG_H / 32, NPLANES);   // 8 x 16 x 48 = 6144 blocks
    ssim_main<<<grid, BLOCK, 0, stream>>>(img1, img2, bsums);
    ssim_finalize<<<1, BLOCK, 0, stream>>>(bsums, out, 6144);
}